// Round 6
// baseline (145.380 us; speedup 1.0000x reference)
//
#include <hip/hip_runtime.h>

typedef __attribute__((ext_vector_type(8))) short short8;
typedef __attribute__((ext_vector_type(4))) float floatx4;

#define LEAKY 0.2f
#define NEGM -9e15f

// --- bf16 helpers (RNE, finite inputs) ---
__device__ __forceinline__ unsigned short f2bf(float f) {
  unsigned int u = __float_as_uint(f);
  u = u + 0x7FFFu + ((u >> 16) & 1u);
  return (unsigned short)(u >> 16);
}
__device__ __forceinline__ float bf2f(short s) {
  return __uint_as_float(((unsigned int)(unsigned short)s) << 16);
}

// ---------------------------------------------------------------------------
// Prep (unchanged, known-good): h fp32 -> Hsw (row-major bf16, row-XOR baked)
//                                      -> HTsw (transposed bf16, row-XOR baked)
// ---------------------------------------------------------------------------
__global__ __launch_bounds__(256) void prep_kernel(
    const float* __restrict__ h, unsigned short* __restrict__ Hsw,
    unsigned short* __restrict__ HTsw) {
  const int b = blockIdx.x >> 2, q = blockIdx.x & 3;
  const int t = threadIdx.x;
  const float* hb = h + b * 65536;
  unsigned short* Hb = Hsw + b * 65536;
  unsigned short* HTb = HTsw + b * 65536;
#pragma unroll
  for (int j = 0; j < 8; ++j) {
    int c = t + j * 256;
    int m = 64 * q + (c >> 5);
    int d0 = (c & 31) * 8;
    const float4* src = (const float4*)(hb + m * 256 + d0);
    float4 x = src[0], y = src[1];
    short8 v;
    v[0] = (short)f2bf(x.x); v[1] = (short)f2bf(x.y);
    v[2] = (short)f2bf(x.z); v[3] = (short)f2bf(x.w);
    v[4] = (short)f2bf(y.x); v[5] = (short)f2bf(y.y);
    v[6] = (short)f2bf(y.z); v[7] = (short)f2bf(y.w);
    *(short8*)(Hb + m * 256 + (d0 ^ ((m & 7) << 3))) = v;
  }
#pragma unroll
  for (int j = 0; j < 8; ++j) {
    int p = t + j * 256;
    int d = 64 * q + (p & 63);
    int m0 = (p >> 6) * 8;
    short8 v;
#pragma unroll
    for (int jj = 0; jj < 8; ++jj) v[jj] = (short)f2bf(hb[(m0 + jj) * 256 + d]);
    *(short8*)(HTb + d * 256 + (m0 ^ ((d & 7) << 3))) = v;
  }
}

// Stage a PAIR of 16 KB tiles (32 rows x 512 B each): waves 0-3 -> tile0,
// waves 4-7 -> tile1. Linear LDS dest (wave-uniform base), width=16.
__device__ __forceinline__ void stage_pair(const unsigned short* g0,
                                           const unsigned short* g1,
                                           unsigned char* s0, unsigned char* s1,
                                           int w, int l) {
  const unsigned char* gsrc = (w < 4) ? (const unsigned char*)g0 : (const unsigned char*)g1;
  unsigned char* ldst = (w < 4) ? s0 : s1;
  const int wo = (w & 3) * 4096;
#pragma unroll
  for (int i = 0; i < 4; ++i) {
    const int off = wo + i * 1024;
    __builtin_amdgcn_global_load_lds(
        (const __attribute__((address_space(1))) unsigned int*)(gsrc + off + l * 16),
        (__attribute__((address_space(3))) unsigned int*)(ldst + off), 16, 0, 0);
  }
}

// ---------------------------------------------------------------------------
// Fused v5: block = (b, 64 n-rows), 512 threads = 8 waves.
// wave w: rw = w&3 (16-row group), mh = w>>2 (m- or d-half of 128).
// Phase 1 is FOUR single-k passes: Ak[8] = 32 VGPR. Peak live ~110 < the
// 128-VGPR budget the compiler insists on (v3: 220 live -> 95 MB spill;
// v4: ~140 live -> 28 MB spill; both at VGPR_Count=128).
// acc split by ks-parity keeps 4 independent MFMA chains.
// LDS: [0,32K) A then alpha; [32K,96K) B tile-pair double buffer;
//      [96K,100K) a fp32; [100K,100.5K) pmax; [100.5K,101K) psum/psq.
// ---------------------------------------------------------------------------
__global__ __launch_bounds__(512) void fused_kernel(
    const float* __restrict__ h, const int* __restrict__ adj,
    const float* __restrict__ a, float* __restrict__ out,
    const unsigned short* __restrict__ Hsw, const unsigned short* __restrict__ HTsw) {
  __shared__ __align__(16) unsigned char lds[103424];
  unsigned short* ldsU = (unsigned short*)lds;
  unsigned char* Bbase = lds + 32768;
  float* aLds = (float*)(lds + 98304);
  float* pmax = (float*)(lds + 102400);  // [64][2]
  float* psum = (float*)(lds + 102912);  // [64][2] (reused as psq)

  const int tid = threadIdx.x;
  const int w = tid >> 6, l = tid & 63;
  const int l16 = l & 15, lhi = l >> 4;
  const int rw = w & 3, mh = w >> 2;
  // XCD swizzle: 4 blocks of same b co-resident on one XCD (grid 256)
  const int id = blockIdx.x;
  const int b = (id & 7) + 8 * (id >> 5);
  const int n0 = ((id >> 3) & 3) * 64;

  const float* hb = h + b * 65536;
  const int* adjb = adj + b * 65536;
  const unsigned short* HswB = Hsw + b * 65536;
  const unsigned short* HTswB = HTsw + b * 65536;

  // prologue: stage phase-1 pair 0 (tiles m:0..31 and m:128..159)
  stage_pair(HswB, HswB + 4 * 32 * 256, Bbase, Bbase + 16384, w, l);

  // stage A rows (n0..n0+63) straight from Hsw (already bf16 + row-swizzled;
  // n0 % 64 == 0 so baked (row&7) swizzle == local swizzle). 32 KB linear.
  {
    const unsigned char* asrc = (const unsigned char*)(HswB + n0 * 256);
#pragma unroll
    for (int i = 0; i < 4; ++i) {
      const int off = i * 8192 + w * 1024;
      __builtin_amdgcn_global_load_lds(
          (const __attribute__((address_space(1))) unsigned int*)(asrc + off + l * 16),
          (__attribute__((address_space(3))) unsigned int*)(lds + off), 16, 0, 0);
    }
  }
  if (tid < 256) ((float4*)aLds)[tid] = ((const float4*)a)[tid];

  // adj values packed 4-bit: adjp[it] nibble (cf*4+r) = adj in [0,4]
  unsigned int adjp[4] = {0u, 0u, 0u, 0u};
  {
    const int* adjrow = adjb + (n0 + rw * 16 + lhi * 4) * 256;
#pragma unroll
    for (int it = 0; it < 4; ++it)
#pragma unroll
      for (int cf = 0; cf < 2; ++cf)
#pragma unroll
        for (int r = 0; r < 4; ++r) {
          unsigned int v = (unsigned int)adjrow[r * 256 + mh * 128 + it * 32 + cf * 16 + l16];
          adjp[it] |= v << ((cf * 4 + r) * 4);
        }
  }
  __syncthreads();  // A + a + pair 0 ready (barrier drains vmcnt)

  const int arow = rw * 16 + l16;
  const int swzA = (arow & 7) << 3;
  floatx4 logits[8];

  // ---- Phase 1: four single-k passes x 4 m-tile-pair iterations ----
#pragma unroll
  for (int p = 0; p < 4; ++p) {
    // build Ak for k = p (reads A-region + aLds; both stable all of phase 1)
    short8 Ak[8];
#pragma unroll
    for (int ks = 0; ks < 8; ++ks) {
      int d0 = ks * 32 + lhi * 8;
      short8 hv = *(const short8*)(ldsU + arow * 256 + (d0 ^ swzA));
      const float4* a4 = (const float4*)(aLds + p * 256 + d0);
      float4 pa = a4[0], qa = a4[1];
      short8 o;
      o[0] = (short)f2bf(bf2f(hv[0]) * pa.x);  o[1] = (short)f2bf(bf2f(hv[1]) * pa.y);
      o[2] = (short)f2bf(bf2f(hv[2]) * pa.z);  o[3] = (short)f2bf(bf2f(hv[3]) * pa.w);
      o[4] = (short)f2bf(bf2f(hv[4]) * qa.x);  o[5] = (short)f2bf(bf2f(hv[5]) * qa.y);
      o[6] = (short)f2bf(bf2f(hv[6]) * qa.z);  o[7] = (short)f2bf(bf2f(hv[7]) * qa.w);
      Ak[ks] = o;
    }
#pragma unroll
    for (int it = 0; it < 4; ++it) {
      const int g = p * 4 + it;       // global step 0..15 over the same 4 pairs
      const int cur = g & 1;
      if (g < 15) {
        const int nt = (g + 1) & 3;
        stage_pair(HswB + nt * 32 * 256, HswB + (nt + 4) * 32 * 256,
                   Bbase + (1 - cur) * 32768, Bbase + (1 - cur) * 32768 + 16384, w, l);
      }
      floatx4 acc[2][2];  // [cf][ks&1] -> 4 independent MFMA chains
#pragma unroll
      for (int cf = 0; cf < 2; ++cf)
#pragma unroll
        for (int e = 0; e < 2; ++e) {
          floatx4 z = {0.f, 0.f, 0.f, 0.f};
          acc[cf][e] = z;
        }
      const unsigned short* Bt = (const unsigned short*)(Bbase + cur * 32768 + mh * 16384);
#pragma unroll
      for (int ks = 0; ks < 8; ++ks) {
        int d0 = ks * 32 + lhi * 8;
        int swzB = (l16 & 7) << 3;
        short8 b0 = *(const short8*)(Bt + l16 * 256 + (d0 ^ swzB));
        short8 b1 = *(const short8*)(Bt + (16 + l16) * 256 + (d0 ^ swzB));
        acc[0][ks & 1] = __builtin_amdgcn_mfma_f32_16x16x32_bf16(Ak[ks], b0, acc[0][ks & 1], 0, 0, 0);
        acc[1][ks & 1] = __builtin_amdgcn_mfma_f32_16x16x32_bf16(Ak[ks], b1, acc[1][ks & 1], 0, 0, 0);
      }
      // incremental merge: pass p handles adj value p+1
#pragma unroll
      for (int cf = 0; cf < 2; ++cf)
#pragma unroll
        for (int r = 0; r < 4; ++r) {
          unsigned int av = (adjp[it] >> ((cf * 4 + r) * 4)) & 15u;
          float e0 = acc[cf][0][r] + acc[cf][1][r];
          float l0 = e0 > 0.f ? e0 : LEAKY * e0;
          float s = (p == 0) ? NEGM : logits[it * 2 + cf][r];
          s = (av == (unsigned)(p + 1)) ? l0 : s;
          logits[it * 2 + cf][r] = s;
        }
      __syncthreads();
    }
  }

  // issue phase-2 pair 0 (HT tiles d:0..31 and d:128..159); overlaps softmax
  stage_pair(HTswB, HTswB + 4 * 32 * 256, Bbase, Bbase + 16384, w, l);

  // ---- softmax across both m-halves via LDS partials ----
  const int row0 = rw * 16 + lhi * 4;
#pragma unroll
  for (int r = 0; r < 4; ++r) {
    float m = logits[0][r];
#pragma unroll
    for (int f = 1; f < 8; ++f) m = fmaxf(m, logits[f][r]);
#pragma unroll
    for (int s = 1; s < 16; s <<= 1) m = fmaxf(m, __shfl_xor(m, s));
    if (l16 == 0) pmax[(row0 + r) * 2 + mh] = m;
  }
  __syncthreads();
#pragma unroll
  for (int r = 0; r < 4; ++r) {
    float gm = fmaxf(pmax[(row0 + r) * 2], pmax[(row0 + r) * 2 + 1]);
    float s = 0.f;
#pragma unroll
    for (int f = 0; f < 8; ++f) {
      float e = __expf(logits[f][r] - gm);
      logits[f][r] = e;
      s += e;
    }
#pragma unroll
    for (int sh = 1; sh < 16; sh <<= 1) s += __shfl_xor(s, sh);
    if (l16 == 0) psum[(row0 + r) * 2 + mh] = s;
  }
  __syncthreads();
  float inv[4];
#pragma unroll
  for (int r = 0; r < 4; ++r)
    inv[r] = 1.f / (psum[(row0 + r) * 2] + psum[(row0 + r) * 2 + 1]);
  // alpha bf16 swizzled into A-region: row, col m = mh*128 + f*16 + l16
#pragma unroll
  for (int f = 0; f < 8; ++f)
#pragma unroll
    for (int r = 0; r < 4; ++r) {
      int row = row0 + r;
      int mcol = mh * 128 + f * 16 + l16;
      ldsU[row * 256 + (mcol ^ ((row & 7) << 3))] = f2bf(logits[f][r] * inv[r]);
    }
  __syncthreads();

  // ---- Phase 2: out = alpha @ H; wave covers [16 rows][128 d (half mh)] ----
  short8 af[8];
#pragma unroll
  for (int ks = 0; ks < 8; ++ks) {
    int m0 = ks * 32 + lhi * 8;
    af[ks] = *(const short8*)(ldsU + arow * 256 + (m0 ^ swzA));
  }
  floatx4 oa[8];
#pragma unroll
  for (int f = 0; f < 8; ++f) {
    floatx4 z = {0.f, 0.f, 0.f, 0.f};
    oa[f] = z;
  }
#pragma unroll
  for (int it = 0; it < 4; ++it) {
    const int cur = it & 1;
    if (it < 3)
      stage_pair(HTswB + (it + 1) * 32 * 256, HTswB + (it + 5) * 32 * 256,
                 Bbase + (1 - cur) * 32768, Bbase + (1 - cur) * 32768 + 16384, w, l);
    const unsigned short* Bt = (const unsigned short*)(Bbase + cur * 32768 + mh * 16384);
#pragma unroll
    for (int cf = 0; cf < 2; ++cf)
#pragma unroll
      for (int ks = 0; ks < 8; ++ks) {
        int m0 = ks * 32 + lhi * 8;
        short8 bf = *(const short8*)(Bt + (cf * 16 + l16) * 256 + (m0 ^ ((l16 & 7) << 3)));
        oa[it * 2 + cf] = __builtin_amdgcn_mfma_f32_16x16x32_bf16(af[ks], bf, oa[it * 2 + cf], 0, 0, 0);
      }
    __syncthreads();
  }

  // ---- epilogue: L2 normalize (cross d-half combine) + residual ----
  float ssq[4] = {0.f, 0.f, 0.f, 0.f};
#pragma unroll
  for (int f = 0; f < 8; ++f)
#pragma unroll
    for (int r = 0; r < 4; ++r) ssq[r] += oa[f][r] * oa[f][r];
#pragma unroll
  for (int r = 0; r < 4; ++r) {
#pragma unroll
    for (int s = 1; s < 16; s <<= 1) ssq[r] += __shfl_xor(ssq[r], s);
    if (l16 == 0) psum[(row0 + r) * 2 + mh] = ssq[r];
  }
  __syncthreads();
  float innv[4];
#pragma unroll
  for (int r = 0; r < 4; ++r) {
    float tot = psum[(row0 + r) * 2] + psum[(row0 + r) * 2 + 1];
    innv[r] = 1.f / fmaxf(sqrtf(tot), 1e-12f);
  }
  float* ob = out + b * 65536;
#pragma unroll
  for (int f = 0; f < 8; ++f)
#pragma unroll
    for (int r = 0; r < 4; ++r) {
      int n = n0 + row0 + r;
      int d = mh * 128 + f * 16 + l16;
      ob[n * 256 + d] = oa[f][r] * innv[r] + hb[n * 256 + d];
    }
}

extern "C" void kernel_launch(void* const* d_in, const int* in_sizes, int n_in,
                              void* d_out, int out_size, void* d_ws, size_t ws_size,
                              hipStream_t stream) {
  const float* h = (const float*)d_in[0];
  const int* adj = (const int*)d_in[1];
  const float* a = (const float*)d_in[2];
  float* out = (float*)d_out;
  unsigned short* Hsw = (unsigned short*)d_ws;
  unsigned short* HTsw = Hsw + 64 * 256 * 256;
  prep_kernel<<<256, 256, 0, stream>>>(h, Hsw, HTsw);
  fused_kernel<<<256, 512, 0, stream>>>(h, adj, a, out, Hsw, HTsw);
}

// Round 7
// 110.411 us; speedup vs baseline: 1.3167x; 1.3167x over previous
//
#include <hip/hip_runtime.h>

typedef __attribute__((ext_vector_type(8))) short short8;
typedef __attribute__((ext_vector_type(4))) float floatx4;

#define LEAKY 0.2f
#define NEGM -9e15f
#define LSTRIDE 260  // padded fp32 logits stride (kills 4-way ds bank conflicts)

// --- bf16 helpers (RNE, finite inputs) ---
__device__ __forceinline__ unsigned short f2bf(float f) {
  unsigned int u = __float_as_uint(f);
  u = u + 0x7FFFu + ((u >> 16) & 1u);
  return (unsigned short)(u >> 16);
}
__device__ __forceinline__ float bf2f(short s) {
  return __uint_as_float(((unsigned int)(unsigned short)s) << 16);
}

// ---------------------------------------------------------------------------
// Prep (unchanged, known-good): h fp32 -> Hsw (row-major bf16, row-XOR baked)
//                                      -> HTsw (transposed bf16, row-XOR baked)
// ---------------------------------------------------------------------------
__global__ __launch_bounds__(256) void prep_kernel(
    const float* __restrict__ h, unsigned short* __restrict__ Hsw,
    unsigned short* __restrict__ HTsw) {
  const int b = blockIdx.x >> 2, q = blockIdx.x & 3;
  const int t = threadIdx.x;
  const float* hb = h + b * 65536;
  unsigned short* Hb = Hsw + b * 65536;
  unsigned short* HTb = HTsw + b * 65536;
#pragma unroll
  for (int j = 0; j < 8; ++j) {
    int c = t + j * 256;
    int m = 64 * q + (c >> 5);
    int d0 = (c & 31) * 8;
    const float4* src = (const float4*)(hb + m * 256 + d0);
    float4 x = src[0], y = src[1];
    short8 v;
    v[0] = (short)f2bf(x.x); v[1] = (short)f2bf(x.y);
    v[2] = (short)f2bf(x.z); v[3] = (short)f2bf(x.w);
    v[4] = (short)f2bf(y.x); v[5] = (short)f2bf(y.y);
    v[6] = (short)f2bf(y.z); v[7] = (short)f2bf(y.w);
    *(short8*)(Hb + m * 256 + (d0 ^ ((m & 7) << 3))) = v;
  }
#pragma unroll
  for (int j = 0; j < 8; ++j) {
    int p = t + j * 256;
    int d = 64 * q + (p & 63);
    int m0 = (p >> 6) * 8;
    short8 v;
#pragma unroll
    for (int jj = 0; jj < 8; ++jj) v[jj] = (short)f2bf(hb[(m0 + jj) * 256 + d]);
    *(short8*)(HTb + d * 256 + (m0 ^ ((d & 7) << 3))) = v;
  }
}

// Stage ONE 16 KB tile with all 8 waves (2 KB each). Linear dest, width=16.
__device__ __forceinline__ void stage_tile(const unsigned short* g,
                                           unsigned char* s, int w, int l) {
  const unsigned char* gs = (const unsigned char*)g;
#pragma unroll
  for (int i = 0; i < 2; ++i) {
    const int off = w * 2048 + i * 1024;
    __builtin_amdgcn_global_load_lds(
        (const __attribute__((address_space(1))) unsigned int*)(gs + off + l * 16),
        (__attribute__((address_space(3))) unsigned int*)(s + off), 16, 0, 0);
  }
}

// Stage a PAIR of 16 KB tiles: waves 0-3 -> tile0, waves 4-7 -> tile1.
__device__ __forceinline__ void stage_pair(const unsigned short* g0,
                                           const unsigned short* g1,
                                           unsigned char* s0, unsigned char* s1,
                                           int w, int l) {
  const unsigned char* gsrc = (w < 4) ? (const unsigned char*)g0 : (const unsigned char*)g1;
  unsigned char* ldst = (w < 4) ? s0 : s1;
  const int wo = (w & 3) * 4096;
#pragma unroll
  for (int i = 0; i < 4; ++i) {
    const int off = wo + i * 1024;
    __builtin_amdgcn_global_load_lds(
        (const __attribute__((address_space(1))) unsigned int*)(gsrc + off + l * 16),
        (__attribute__((address_space(3))) unsigned int*)(ldst + off), 16, 0, 0);
  }
}

// ---------------------------------------------------------------------------
// Fused v6: block = (b, 64 n-rows), 512 threads = 8 waves.
// Phase 1: wave w = (rw = w&3 row-group, kp = w>>2 k-pair). Each wave holds
// only Ak[2][8] (64 VGPR) for k = {2kp, 2kp+1}; B tiles (32 m-rows) staged
// ONCE, consumed by all 8 waves; merged logits go straight to LDS L[64][260]
// fp32 (kp=0 writes value-or-NEGM, barrier, kp=1 overwrites where adj>=3).
// -> no long-lived accumulator registers -> no per-iteration spill
// (v4/v5: logits[8] in regs spilled ~45 B/thread/iter under the fixed
// 128-VGPR budget -> 45-99 MB scratch writes).
// Phase 2 (unchanged from v5): alpha @ H with HT pair staging in dead L region.
// LDS: [0,32K) A then alpha; [32K,99328) L (softmax) then HT dbuf (phase 2);
//      [99328,132096) phase-1 B dbuf; [132096,136192) a fp32; [136192,+512) psum.
// ---------------------------------------------------------------------------
__global__ __launch_bounds__(512) void fused_kernel(
    const float* __restrict__ h, const int* __restrict__ adj,
    const float* __restrict__ a, float* __restrict__ out,
    const unsigned short* __restrict__ Hsw, const unsigned short* __restrict__ HTsw) {
  __shared__ __align__(16) unsigned char lds[136704];
  unsigned short* ldsU = (unsigned short*)lds;       // A region [64][256] bf16
  float* Lf = (float*)(lds + 32768);                 // [64][260] fp32
  unsigned char* B1 = lds + 99328;                   // phase-1 tile dbuf 2x16K
  unsigned char* B2 = lds + 32768;                   // phase-2 pair dbuf 2x32K
  float* aLds = (float*)(lds + 132096);              // a [4][256] fp32
  float* psum = (float*)(lds + 136192);              // [64][2]

  const int tid = threadIdx.x;
  const int w = tid >> 6, l = tid & 63;
  const int l16 = l & 15, lhi = l >> 4;
  const int rw = w & 3, kp = w >> 2;
  // XCD swizzle: 4 blocks of same b co-resident on one XCD (grid 256)
  const int id = blockIdx.x;
  const int b = (id & 7) + 8 * (id >> 5);
  const int n0 = ((id >> 3) & 3) * 64;

  const float* hb = h + b * 65536;
  const int* adjb = adj + b * 65536;
  const unsigned short* HswB = Hsw + b * 65536;
  const unsigned short* HTswB = HTsw + b * 65536;

  // prologue: stage phase-1 tile 0 (m 0..31)
  stage_tile(HswB, B1, w, l);
  // stage A rows (n0..n0+63) from Hsw (bf16, row-swizzle baked). 32 KB linear.
  {
    const unsigned char* asrc = (const unsigned char*)(HswB + n0 * 256);
#pragma unroll
    for (int i = 0; i < 4; ++i) {
      const int off = i * 8192 + w * 1024;
      __builtin_amdgcn_global_load_lds(
          (const __attribute__((address_space(1))) unsigned int*)(asrc + off + l * 16),
          (__attribute__((address_space(3))) unsigned int*)(lds + off), 16, 0, 0);
    }
  }
  if (tid < 256) ((float4*)aLds)[tid] = ((const float4*)a)[tid];
  __syncthreads();  // A + a + tile 0 ready

  const int arow = rw * 16 + l16;
  const int swzA = (arow & 7) << 3;
  const int swzB = (l16 & 7) << 3;
  const int row0 = rw * 16 + lhi * 4;

  // Ak for k = 2kp, 2kp+1 (built once; A region stable through phase 1)
  short8 Ak[2][8];
#pragma unroll
  for (int ks = 0; ks < 8; ++ks) {
    int d0 = ks * 32 + lhi * 8;
    short8 hv = *(const short8*)(ldsU + arow * 256 + (d0 ^ swzA));
#pragma unroll
    for (int kk = 0; kk < 2; ++kk) {
      const float4* a4 = (const float4*)(aLds + (kp * 2 + kk) * 256 + d0);
      float4 pa = a4[0], qa = a4[1];
      short8 o;
      o[0] = (short)f2bf(bf2f(hv[0]) * pa.x);  o[1] = (short)f2bf(bf2f(hv[1]) * pa.y);
      o[2] = (short)f2bf(bf2f(hv[2]) * pa.z);  o[3] = (short)f2bf(bf2f(hv[3]) * pa.w);
      o[4] = (short)f2bf(bf2f(hv[4]) * qa.x);  o[5] = (short)f2bf(bf2f(hv[5]) * qa.y);
      o[6] = (short)f2bf(bf2f(hv[6]) * qa.z);  o[7] = (short)f2bf(bf2f(hv[7]) * qa.w);
      Ak[kk][ks] = o;
    }
  }

  // ---- Phase 1: 8 tiles (32 m-rows each), staged once, all waves compute ----
  const int* adjrow = adjb + (n0 + row0) * 256;
#pragma unroll
  for (int t = 0; t < 8; ++t) {
    const int cur = t & 1;
    if (t < 7) stage_tile(HswB + (t + 1) * 32 * 256, B1 + (1 - cur) * 16384, w, l);
    const unsigned short* Bt = (const unsigned short*)(B1 + cur * 16384);
    floatx4 acc[2][2];  // [cf][kk]
#pragma unroll
    for (int cf = 0; cf < 2; ++cf)
#pragma unroll
      for (int kk = 0; kk < 2; ++kk) {
        floatx4 z = {0.f, 0.f, 0.f, 0.f};
        acc[cf][kk] = z;
      }
#pragma unroll
    for (int ks = 0; ks < 8; ++ks) {
      int d0 = ks * 32 + lhi * 8;
      short8 b0 = *(const short8*)(Bt + l16 * 256 + (d0 ^ swzB));
      short8 b1 = *(const short8*)(Bt + (16 + l16) * 256 + (d0 ^ swzB));
      acc[0][0] = __builtin_amdgcn_mfma_f32_16x16x32_bf16(Ak[0][ks], b0, acc[0][0], 0, 0, 0);
      acc[0][1] = __builtin_amdgcn_mfma_f32_16x16x32_bf16(Ak[1][ks], b0, acc[0][1], 0, 0, 0);
      acc[1][0] = __builtin_amdgcn_mfma_f32_16x16x32_bf16(Ak[0][ks], b1, acc[1][0], 0, 0, 0);
      acc[1][1] = __builtin_amdgcn_mfma_f32_16x16x32_bf16(Ak[1][ks], b1, acc[1][1], 0, 0, 0);
    }
    // merge into LDS logits: kp=0 writes (sel or NEGM); kp=1 overwrites adj>=3
    int adjv[2][4];
#pragma unroll
    for (int cf = 0; cf < 2; ++cf)
#pragma unroll
      for (int r = 0; r < 4; ++r)
        adjv[cf][r] = adjrow[r * 256 + t * 32 + cf * 16 + l16];
    if (kp == 0) {
#pragma unroll
      for (int cf = 0; cf < 2; ++cf)
#pragma unroll
        for (int r = 0; r < 4; ++r) {
          int av = adjv[cf][r];
          float e0 = acc[cf][0][r], e1 = acc[cf][1][r];
          float l0 = e0 > 0.f ? e0 : LEAKY * e0;
          float l1 = e1 > 0.f ? e1 : LEAKY * e1;
          float s = (av == 1) ? l0 : (av == 2) ? l1 : NEGM;
          Lf[(row0 + r) * LSTRIDE + t * 32 + cf * 16 + l16] = s;
        }
    }
    __syncthreads();  // ordering: kp=0 writes land before kp=1's
    if (kp == 1) {
#pragma unroll
      for (int cf = 0; cf < 2; ++cf)
#pragma unroll
        for (int r = 0; r < 4; ++r) {
          int av = adjv[cf][r];
          float e0 = acc[cf][0][r], e1 = acc[cf][1][r];
          float l0 = e0 > 0.f ? e0 : LEAKY * e0;
          float l1 = e1 > 0.f ? e1 : LEAKY * e1;
          if (av >= 3) Lf[(row0 + r) * LSTRIDE + t * 32 + cf * 16 + l16] = (av == 3) ? l0 : l1;
        }
    }
    __syncthreads();  // L complete for this tile; staging buffer safe to swap
  }

  // ---- softmax: wave owns 8 rows; lane = (row l&7, m-chunk (l>>3)*32) ----
  {
    const int srow = rw * 16 + kp * 8 + (l & 7);
    const int chunk = l >> 3;  // 0..7
    const float* Lr = Lf + srow * LSTRIDE + chunk * 32;
    float4 v[8];
#pragma unroll
    for (int j = 0; j < 8; ++j) v[j] = *(const float4*)(Lr + j * 4);
    float mx = -3.4e38f;
#pragma unroll
    for (int j = 0; j < 8; ++j)
      mx = fmaxf(mx, fmaxf(fmaxf(v[j].x, v[j].y), fmaxf(v[j].z, v[j].w)));
#pragma unroll
    for (int s = 8; s < 64; s <<= 1) mx = fmaxf(mx, __shfl_xor(mx, s));
    float sum = 0.f;
#pragma unroll
    for (int j = 0; j < 8; ++j) {
      v[j].x = __expf(v[j].x - mx); v[j].y = __expf(v[j].y - mx);
      v[j].z = __expf(v[j].z - mx); v[j].w = __expf(v[j].w - mx);
      sum += v[j].x + v[j].y + v[j].z + v[j].w;
    }
#pragma unroll
    for (int s = 8; s < 64; s <<= 1) sum += __shfl_xor(sum, s);
    float inv = 1.f / sum;
    const int sswz = (srow & 7) << 3;
#pragma unroll
    for (int j = 0; j < 4; ++j) {
      short8 o;
      o[0] = (short)f2bf(v[2 * j].x * inv);     o[1] = (short)f2bf(v[2 * j].y * inv);
      o[2] = (short)f2bf(v[2 * j].z * inv);     o[3] = (short)f2bf(v[2 * j].w * inv);
      o[4] = (short)f2bf(v[2 * j + 1].x * inv); o[5] = (short)f2bf(v[2 * j + 1].y * inv);
      o[6] = (short)f2bf(v[2 * j + 1].z * inv); o[7] = (short)f2bf(v[2 * j + 1].w * inv);
      int col = chunk * 32 + j * 8;
      *(short8*)(ldsU + srow * 256 + (col ^ sswz)) = o;
    }
  }
  __syncthreads();  // alpha in A-region complete; L region now dead

  // ---- Phase 2: out = alpha @ H; wave = (rw rows, mh = kp d-half) ----
  const int mh = kp;
  short8 af[8];
#pragma unroll
  for (int ks = 0; ks < 8; ++ks) {
    int m0 = ks * 32 + lhi * 8;
    af[ks] = *(const short8*)(ldsU + arow * 256 + (m0 ^ swzA));
  }
  stage_pair(HTswB, HTswB + 4 * 32 * 256, B2, B2 + 16384, w, l);
  __syncthreads();  // pair 0 staged (drains vmcnt)

  floatx4 oa[8];
#pragma unroll
  for (int f = 0; f < 8; ++f) {
    floatx4 z = {0.f, 0.f, 0.f, 0.f};
    oa[f] = z;
  }
#pragma unroll
  for (int it = 0; it < 4; ++it) {
    const int cur = it & 1;
    if (it < 3)
      stage_pair(HTswB + (it + 1) * 32 * 256, HTswB + (it + 5) * 32 * 256,
                 B2 + (1 - cur) * 32768, B2 + (1 - cur) * 32768 + 16384, w, l);
    const unsigned short* Bt = (const unsigned short*)(B2 + cur * 32768 + mh * 16384);
#pragma unroll
    for (int cf = 0; cf < 2; ++cf)
#pragma unroll
      for (int ks = 0; ks < 8; ++ks) {
        int m0 = ks * 32 + lhi * 8;
        short8 bf = *(const short8*)(Bt + (cf * 16 + l16) * 256 + (m0 ^ swzB));
        oa[it * 2 + cf] = __builtin_amdgcn_mfma_f32_16x16x32_bf16(af[ks], bf, oa[it * 2 + cf], 0, 0, 0);
      }
    __syncthreads();
  }

  // ---- epilogue: L2 normalize (cross d-half combine) + residual ----
  float ssq[4] = {0.f, 0.f, 0.f, 0.f};
#pragma unroll
  for (int f = 0; f < 8; ++f)
#pragma unroll
    for (int r = 0; r < 4; ++r) ssq[r] += oa[f][r] * oa[f][r];
#pragma unroll
  for (int r = 0; r < 4; ++r) {
#pragma unroll
    for (int s = 1; s < 16; s <<= 1) ssq[r] += __shfl_xor(ssq[r], s);
    if (l16 == 0) psum[(row0 + r) * 2 + mh] = ssq[r];
  }
  __syncthreads();
  float innv[4];
#pragma unroll
  for (int r = 0; r < 4; ++r) {
    float tot = psum[(row0 + r) * 2] + psum[(row0 + r) * 2 + 1];
    innv[r] = 1.f / fmaxf(sqrtf(tot), 1e-12f);
  }
  float* ob = out + b * 65536;
#pragma unroll
  for (int f = 0; f < 8; ++f)
#pragma unroll
    for (int r = 0; r < 4; ++r) {
      int n = n0 + row0 + r;
      int d = mh * 128 + f * 16 + l16;
      ob[n * 256 + d] = oa[f][r] * innv[r] + hb[n * 256 + d];
    }
}

extern "C" void kernel_launch(void* const* d_in, const int* in_sizes, int n_in,
                              void* d_out, int out_size, void* d_ws, size_t ws_size,
                              hipStream_t stream) {
  const float* h = (const float*)d_in[0];
  const int* adj = (const int*)d_in[1];
  const float* a = (const float*)d_in[2];
  float* out = (float*)d_out;
  unsigned short* Hsw = (unsigned short*)d_ws;
  unsigned short* HTsw = Hsw + 64 * 256 * 256;
  prep_kernel<<<256, 256, 0, stream>>>(h, Hsw, HTsw);
  fused_kernel<<<256, 512, 0, stream>>>(h, adj, a, out, Hsw, HTsw);
}